// Round 4
// baseline (107.886 us; speedup 1.0000x reference)
//
#include <hip/hip_runtime.h>
#include <hip/hip_bf16.h>

// RoIPool max over boolean cell masks (harness bf16-ifies floats AND bools).
// B=8 images, C=256 channels, H=W=64 (HW=4096), N=128 cells (16/image).
// Fused single kernel, no d_ws. Runtime dtype detection kept for robustness:
//   - mask element size s in {1,2,4} from byte-lane OR signature of first 1KiB
//   - feature dtype (bf16 vs f32) from exponent-byte statistics; output follows.
// R4 change vs R3: inner (pixel,cell) decode in bit domain:
//   v_bfe_i32 (sign-extend mask bit) + v_bfi_b32 (select f / -inf) + v_max3_f32
//   (pair two pixels) = ~2.5 VALU ops per px-cell vs ~4 before.

#define HW    4096
#define BIMG  8
#define CCH   256
#define NCELL 128
#define CG    4      // channels per block

__device__ __forceinline__ void cell_range(const int* counts, int b, int& start, int& cnt) {
    start = 0;
    for (int i = 0; i < b; ++i) start += counts[i];
    if (start > NCELL) start = NCELL;
    cnt = counts[b];
    // jnp.repeat(..., total_repeat_length=N) pads with the last value:
    if (b == BIMG - 1 && start + cnt < NCELL) cnt = NCELL - start;
    if (cnt > 16) cnt = 16;
    if (start + cnt > NCELL) cnt = NCELL - start;
    if (cnt < 0) cnt = 0;
}

__global__ __launch_bounds__(256)
void roipool_fused(const void* __restrict__ featv,
                   const void* __restrict__ maskv,
                   const int* __restrict__ counts,
                   void* __restrict__ outv) {
    const int b   = blockIdx.y;
    const int cg0 = blockIdx.x * CG;
    const int tid = threadIdx.x;
    const float NEG = -__builtin_inff();
    const unsigned NEGI = 0xFF800000u;   // f32 -inf bit pattern

    __shared__ int s_msize;   // mask element size: 1, 2, or 4 bytes
    __shared__ int s_fbf16;   // features (and output) are bf16?

    // ---- dtype detection (wave 0 only; ~1.25 KiB of reads, L2-hot) ----
    if (tid < 64) {
        const unsigned* mw = (const unsigned*)maskv;
        unsigned ow = mw[tid * 4] | mw[tid * 4 + 1] | mw[tid * 4 + 2] | mw[tid * 4 + 3];
        #pragma unroll
        for (int d = 32; d >= 1; d >>= 1) ow |= __shfl_down(ow, d, 64);
        const unsigned* fw_ = (const unsigned*)featv;
        unsigned w = fw_[tid];
        unsigned eb = (w >> 8) & 0x7F;
        int hit = (eb >= 0x3B && eb <= 0x41);
        unsigned long long bm = __ballot(hit);
        if (tid == 0) {
            unsigned or0 = ow & 0xFFu, or1 = (ow >> 8) & 0xFFu;
            int s;
            if (or1 == 0)                         s = 4;  // int32/f32 masks
            else if (or0 == 0x80 || or0 == 0x00)  s = 2;  // bf16 (3F80) / f16 (3C00)
            else                                  s = 1;  // bool/uint8
            s_msize = s;
            s_fbf16 = (__popcll(bm) >= 48);
        }
    }
    __syncthreads();
    const int msize = s_msize;
    const int fbf16 = s_fbf16;

    int start, cnt;
    cell_range(counts, b, start, cnt);

    // ---- pack this thread's 16 pixels (p = tid*16 .. +15) x 16 cells into registers
    unsigned pm[16];
    #pragma unroll
    for (int i = 0; i < 16; ++i) pm[i] = 0;
    const int p0 = tid * 16;
    const unsigned char* mb = (const unsigned char*)maskv;

    if (msize == 1) {
        for (int j = 0; j < cnt; ++j) {
            uint4 mv = *(const uint4*)(mb + ((size_t)(start + j) << 12) + p0);
            unsigned wd[4] = {mv.x, mv.y, mv.z, mv.w};
            #pragma unroll
            for (int i = 0; i < 16; ++i) {
                unsigned byte = (wd[i >> 2] >> ((i & 3) * 8)) & 0xFFu;
                pm[i] |= (byte ? 1u : 0u) << j;
            }
        }
    } else if (msize == 2) {
        for (int j = 0; j < cnt; ++j) {
            const unsigned char* base = mb + (((size_t)(start + j) << 12) + p0) * 2;
            uint4 a  = *(const uint4*)(base);
            uint4 c2 = *(const uint4*)(base + 16);
            unsigned wd[8] = {a.x, a.y, a.z, a.w, c2.x, c2.y, c2.z, c2.w};
            #pragma unroll
            for (int i = 0; i < 16; ++i) {
                unsigned h = (wd[i >> 1] >> ((i & 1) * 16)) & 0xFFFFu;
                pm[i] |= (h ? 1u : 0u) << j;
            }
        }
    } else {
        for (int j = 0; j < cnt; ++j) {
            const unsigned char* base = mb + (((size_t)(start + j) << 12) + p0) * 4;
            #pragma unroll
            for (int q = 0; q < 4; ++q) {
                uint4 a = *(const uint4*)(base + q * 16);
                unsigned wd[4] = {a.x, a.y, a.z, a.w};
                #pragma unroll
                for (int r = 0; r < 4; ++r)
                    pm[q * 4 + r] |= (wd[r] ? 1u : 0u) << j;
            }
        }
    }

    // ---- per-channel: load 16 pixels, 16 running cell-maxes, LDS reduce ----
    __shared__ float red[256 * 17];   // stride 17: <=2-way bank aliasing (free)
    __shared__ float red2[16 * 17];

    for (int cc = 0; cc < CG; ++cc) {
        const int c = cg0 + cc;
        // pixel bit patterns as f32 (even/odd of each pair)
        unsigned pe[8], po[8];
        if (fbf16) {
            const unsigned short* fp = (const unsigned short*)featv
                                     + (((size_t)(b * CCH + c)) << 12) + p0;
            uint4 f0 = *(const uint4*)(fp);
            uint4 f1 = *(const uint4*)(fp + 8);
            unsigned w8[8] = {f0.x, f0.y, f0.z, f0.w, f1.x, f1.y, f1.z, f1.w};
            #pragma unroll
            for (int k = 0; k < 8; ++k) {
                pe[k] = w8[k] << 16;           // even pixel (low bf16) as f32 bits
                po[k] = w8[k] & 0xFFFF0000u;   // odd pixel
            }
        } else {
            const float* fp = (const float*)featv + (((size_t)(b * CCH + c)) << 12) + p0;
            #pragma unroll
            for (int q = 0; q < 4; ++q) {
                uint4 a = *(const uint4*)(fp + q * 4);
                unsigned w4[4] = {a.x, a.y, a.z, a.w};
                pe[q * 2]     = w4[0]; po[q * 2]     = w4[1];
                pe[q * 2 + 1] = w4[2]; po[q * 2 + 1] = w4[3];
            }
        }

        float vmax[16];
        #pragma unroll
        for (int j = 0; j < 16; ++j) vmax[j] = NEG;

        #pragma unroll
        for (int k = 0; k < 8; ++k) {
            const unsigned fe = pe[k], fo = po[k];
            // pixel indices: bf16 path pair k = pixels (2k, 2k+1);
            // f32 path pairs were laid out (4q,4q+1),(4q+2,4q+3) = same pm order
            const unsigned me = pm[2 * k];
            const unsigned mo = pm[2 * k + 1];
            #pragma unroll
            for (int j = 0; j < 16; ++j) {
                // sign-extended mask bit: v_bfe_i32
                unsigned m0 = (unsigned)(((int)(me << (31 - j))) >> 31);
                unsigned m1 = (unsigned)(((int)(mo << (31 - j))) >> 31);
                // bitwise select f / -inf: v_bfi_b32
                float s0 = __uint_as_float((fe & m0) | (NEGI & ~m0));
                float s1 = __uint_as_float((fo & m1) | (NEGI & ~m1));
                // v_max3_f32
                vmax[j] = fmaxf(fmaxf(vmax[j], s0), s1);
            }
        }

        #pragma unroll
        for (int j = 0; j < 16; ++j) red[tid * 17 + j] = vmax[j];
        __syncthreads();
        {
            const int jj = tid & 15;
            const int g  = tid >> 4;
            float m = NEG;
            #pragma unroll
            for (int r = 0; r < 16; ++r)
                m = fmaxf(m, red[(g * 16 + r) * 17 + jj]);
            red2[g * 17 + jj] = m;
        }
        __syncthreads();
        if (tid < 16) {
            float m2 = NEG;
            #pragma unroll
            for (int g2 = 0; g2 < 16; ++g2)
                m2 = fmaxf(m2, red2[g2 * 17 + tid]);
            if (tid < cnt) {
                size_t oi = (size_t)(start + tid) * CCH + c;
                if (fbf16) ((__hip_bfloat16*)outv)[oi] = __float2bfloat16(m2);
                else       ((float*)outv)[oi] = m2;
            }
        }
        __syncthreads();   // red/red2 reused next channel
    }
}

extern "C" void kernel_launch(void* const* d_in, const int* in_sizes, int n_in,
                              void* d_out, int out_size, void* d_ws, size_t ws_size,
                              hipStream_t stream) {
    const void* feat  = d_in[0];
    const void* masks = d_in[1];
    const int* counts = (const int*)d_in[2];

    dim3 grid(CCH / CG, BIMG);   // (64, 8) blocks, 256 threads
    roipool_fused<<<grid, 256, 0, stream>>>(feat, masks, counts, d_out);
}

// Round 5
// 87.099 us; speedup vs baseline: 1.2387x; 1.2387x over previous
//
#include <hip/hip_runtime.h>
#include <hip/hip_bf16.h>

// RoIPool max over boolean cell masks (harness bf16-ifies floats AND bools).
// B=8, C=256, H=W=64 (HW=4096), N=128 cells (16/image).
// R5 structure (fix latency-bound R4: 60us @ 19% VALUBusy, 10% occupancy):
//   kernel 1: pack 16 cell masks/image -> uint16 per pixel in d_ws (64 KB),
//             runs ONCE (was implicitly redone by all 512 blocks in R4).
//   kernel 2: one block per (b,c) = 2048 blocks (4x R4), CG=1, ~60 VGPRs,
//             bit-domain select (bfe_i32 + bfi_b32 + max3_f32).

#define HW    4096
#define BIMG  8
#define CCH   256
#define NCELL 128

__device__ __forceinline__ void cell_range(const int* counts, int b, int& start, int& cnt) {
    start = 0;
    for (int i = 0; i < b; ++i) start += counts[i];
    if (start > NCELL) start = NCELL;
    cnt = counts[b];
    // jnp.repeat(..., total_repeat_length=N) pads with the last value:
    if (b == BIMG - 1 && start + cnt < NCELL) cnt = NCELL - start;
    if (cnt > 16) cnt = 16;
    if (start + cnt > NCELL) cnt = NCELL - start;
    if (cnt < 0) cnt = 0;
}

// ---- kernel 1: bit-pack masks. grid 128x256 threads = 32768 = BIMG*HW ----
__global__ __launch_bounds__(256)
void pack_masks(const void* __restrict__ maskv,
                const int* __restrict__ counts,
                unsigned short* __restrict__ packed) {
    const int idx = blockIdx.x * blockDim.x + threadIdx.x;  // b*HW + p
    const int tid = threadIdx.x;
    const int b = idx >> 12;
    const int p = idx & (HW - 1);

    __shared__ int s_msize;
    // mask element size from byte-lane OR of first 1 KiB (proven R3/R4)
    if (tid < 64) {
        const unsigned* mw = (const unsigned*)maskv;
        unsigned ow = mw[tid * 4] | mw[tid * 4 + 1] | mw[tid * 4 + 2] | mw[tid * 4 + 3];
        #pragma unroll
        for (int d = 32; d >= 1; d >>= 1) ow |= __shfl_down(ow, d, 64);
        if (tid == 0) {
            unsigned or0 = ow & 0xFFu, or1 = (ow >> 8) & 0xFFu;
            int s;
            if (or1 == 0)                         s = 4;  // int32/f32 masks
            else if (or0 == 0x80 || or0 == 0x00)  s = 2;  // bf16 (3F80) / f16 (3C00)
            else                                  s = 1;  // bool/uint8
            s_msize = s;
        }
    }
    __syncthreads();
    const int msize = s_msize;

    int start, cnt;
    cell_range(counts, b, start, cnt);

    unsigned w = 0;
    if (msize == 2) {
        const unsigned short* mh = (const unsigned short*)maskv;
        for (int j = 0; j < cnt; ++j)
            w |= (mh[(size_t)(start + j) * HW + p] ? 1u : 0u) << j;
    } else if (msize == 4) {
        const unsigned* mw = (const unsigned*)maskv;
        for (int j = 0; j < cnt; ++j)
            w |= (mw[(size_t)(start + j) * HW + p] ? 1u : 0u) << j;
    } else {
        const unsigned char* mb = (const unsigned char*)maskv;
        for (int j = 0; j < cnt; ++j)
            w |= (mb[(size_t)(start + j) * HW + p] ? 1u : 0u) << j;
    }
    packed[idx] = (unsigned short)w;
}

// ---- kernel 2: one block per (b, c). grid (256, 8) x 256 threads ----
__global__ __launch_bounds__(256, 4)
void roipool_main(const void* __restrict__ featv,
                  const unsigned short* __restrict__ packed,
                  const int* __restrict__ counts,
                  void* __restrict__ outv) {
    const int c   = blockIdx.x;
    const int b   = blockIdx.y;
    const int tid = threadIdx.x;
    const float NEG = -__builtin_inff();
    const unsigned NEGI = 0xFF800000u;   // f32 -inf bits

    __shared__ int s_fbf16;
    if (tid < 64) {
        // features bf16 iff byte1 of each dword looks like a bf16 exponent byte
        const unsigned* fw_ = (const unsigned*)featv;
        unsigned w = fw_[tid];
        unsigned eb = (w >> 8) & 0x7F;
        unsigned long long bm = __ballot(eb >= 0x3B && eb <= 0x41);
        if (tid == 0) s_fbf16 = (__popcll(bm) >= 48);
    }
    __syncthreads();
    const int fbf16 = s_fbf16;

    int start, cnt;
    cell_range(counts, b, start, cnt);

    const int p0 = tid * 16;   // this thread's 16 pixels

    // packed masks: 16 uint16 = 32 B; dword k holds masks of px (2k, 2k+1)
    uint4 pa = *(const uint4*)(packed + ((size_t)b << 12) + p0);
    uint4 pb = *(const uint4*)(packed + ((size_t)b << 12) + p0 + 8);
    unsigned pmw[8] = {pa.x, pa.y, pa.z, pa.w, pb.x, pb.y, pb.z, pb.w};

    // features as f32 bit patterns: pair k = pixels (2k, 2k+1)
    unsigned pe[8], po[8];
    if (fbf16) {
        const unsigned short* fp = (const unsigned short*)featv
                                 + (((size_t)(b * CCH + c)) << 12) + p0;
        uint4 f0 = *(const uint4*)(fp);
        uint4 f1 = *(const uint4*)(fp + 8);
        unsigned w8[8] = {f0.x, f0.y, f0.z, f0.w, f1.x, f1.y, f1.z, f1.w};
        #pragma unroll
        for (int k = 0; k < 8; ++k) {
            pe[k] = w8[k] << 16;
            po[k] = w8[k] & 0xFFFF0000u;
        }
    } else {
        const float* fp = (const float*)featv + (((size_t)(b * CCH + c)) << 12) + p0;
        #pragma unroll
        for (int q = 0; q < 4; ++q) {
            uint4 a = *(const uint4*)(fp + q * 4);
            pe[q * 2]     = a.x; po[q * 2]     = a.y;
            pe[q * 2 + 1] = a.z; po[q * 2 + 1] = a.w;
        }
    }

    float vmax[16];
    #pragma unroll
    for (int j = 0; j < 16; ++j) vmax[j] = NEG;

    #pragma unroll
    for (int k = 0; k < 8; ++k) {
        const unsigned fe = pe[k], fo = po[k];
        const unsigned mw = pmw[k];   // bits 0..15: px 2k; bits 16..31: px 2k+1
        #pragma unroll
        for (int j = 0; j < 16; ++j) {
            unsigned m0 = (unsigned)(((int)(mw << (31 - j))) >> 31);  // bfe_i32 bit j
            unsigned m1 = (unsigned)(((int)(mw << (15 - j))) >> 31);  // bit j+16
            float s0 = __uint_as_float((fe & m0) | (NEGI & ~m0));     // bfi_b32
            float s1 = __uint_as_float((fo & m1) | (NEGI & ~m1));
            vmax[j] = fmaxf(fmaxf(vmax[j], s0), s1);                  // max3_f32
        }
    }

    // 256 threads x 16 cell-maxes -> 16 values; stride 17 (2-way alias = free)
    __shared__ float red[256 * 17];
    __shared__ float red2[16 * 17];
    #pragma unroll
    for (int j = 0; j < 16; ++j) red[tid * 17 + j] = vmax[j];
    __syncthreads();
    {
        const int jj = tid & 15;
        const int g  = tid >> 4;
        float m = NEG;
        #pragma unroll
        for (int r = 0; r < 16; ++r)
            m = fmaxf(m, red[(g * 16 + r) * 17 + jj]);
        red2[g * 17 + jj] = m;
    }
    __syncthreads();
    if (tid < 16) {
        float m2 = NEG;
        #pragma unroll
        for (int g2 = 0; g2 < 16; ++g2)
            m2 = fmaxf(m2, red2[g2 * 17 + tid]);
        if (tid < cnt) {
            size_t oi = (size_t)(start + tid) * CCH + c;
            if (fbf16) ((__hip_bfloat16*)outv)[oi] = __float2bfloat16(m2);
            else       ((float*)outv)[oi] = m2;
        }
    }
}

extern "C" void kernel_launch(void* const* d_in, const int* in_sizes, int n_in,
                              void* d_out, int out_size, void* d_ws, size_t ws_size,
                              hipStream_t stream) {
    const void* feat  = d_in[0];
    const void* masks = d_in[1];
    const int* counts = (const int*)d_in[2];
    unsigned short* packed = (unsigned short*)d_ws;   // 8*4096*2 = 64 KiB

    pack_masks<<<(BIMG * HW) / 256, 256, 0, stream>>>(masks, counts, packed);

    dim3 grid(CCH, BIMG);   // 2048 blocks, one per (b, c)
    roipool_main<<<grid, 256, 0, stream>>>(feat, packed, counts, d_out);
}